// Round 16
// baseline (89.404 us; speedup 1.0000x reference)
//
#include <hip/hip_runtime.h>
#include <stdint.h>

#define M_DIM 4096
#define I_DIM 1024
#define O_DIM 1024
#define KB 6
#define K_DIM (I_DIM * KB)   // 6144
#define SPLITS 4

typedef __attribute__((ext_vector_type(8))) short short8;
typedef __attribute__((ext_vector_type(4))) float f32x4;
typedef __attribute__((ext_vector_type(2))) float f32x2;
typedef __attribute__((ext_vector_type(4))) unsigned int u32x4;
typedef __attribute__((ext_vector_type(4))) float hfloat4;
typedef __attribute__((ext_vector_type(8))) _Float16 h16x8;
typedef __attribute__((ext_vector_type(4))) _Float16 h16x4;

__device__ __forceinline__ unsigned short f2bf(float f) {
  union { float f; unsigned int u; } v; v.f = f;
  unsigned int u = v.u;
  unsigned int r = (u + 0x7FFFu + ((u >> 16) & 1u)) >> 16;
  return (unsigned short)r;
}

// ---- Kernel 1 (fat): blocks [0,2048): basis planes -> bf16 A[4096][6144]
//                      blocks [2048,3072): coeffs -> bf16 Bt[1024][6144] + bias partials
__global__ __launch_bounds__(256) void k_prep(const float* __restrict__ x,
                                              const float* __restrict__ C,
                                              unsigned short* __restrict__ A,
                                              unsigned short* __restrict__ Bt,
                                              float* __restrict__ partB) {
  const int bid = blockIdx.x;
  if (bid < 2048) {
    int t = bid * 256 + threadIdx.x;
    long e0 = (long)t * 8;
    const hfloat4* xp = (const hfloat4*)(x + e0);
    hfloat4 v0 = xp[0], v1 = xp[1];
    float xv[8];
    xv[0]=v0[0]; xv[1]=v0[1]; xv[2]=v0[2]; xv[3]=v0[3];
    xv[4]=v1[0]; xv[5]=v1[1]; xv[6]=v1[2]; xv[7]=v1[3];
    unsigned short outv[48];
#pragma unroll
    for (int e = 0; e < 8; ++e) {
      float s  = 1.0f / (1.0f + __expf(-xv[e]));
      float b2 = s, b3 = s, b4 = s * s;
      float b5 = fmaf(s, b4, b3 + b2 + 1.0f);
      float b6 = fmaf(s, b5, b4 + b3 + b2 + 1.0f);
      float b7 = fmaf(s, b6, b5 + b4 + b3 + b2);
      float b8 = fmaf(s, b7, b6 + b5 + b4 + b3);
      outv[e*6+0] = f2bf(s);
      outv[e*6+1] = f2bf(b4);
      outv[e*6+2] = f2bf(b5);
      outv[e*6+3] = f2bf(b6);
      outv[e*6+4] = f2bf(b7);
      outv[e*6+5] = f2bf(b8);
    }
    u32x4* dst = (u32x4*)(A + e0 * KB);
    const u32x4* srcv = (const u32x4*)outv;
#pragma unroll
    for (int q = 0; q < 6; ++q) dst[q] = srcv[q];
  } else {
    __shared__ unsigned short tile[32 * 192];
    __shared__ float bred[256];
    int b = bid - 2048;
    int i0 = (b & 31) * 32, o0 = (b >> 5) * 32;
    int t = threadIdx.x;
    int ol = t & 31, ig = t >> 5;
    float bsum = 0.f;
#pragma unroll
    for (int r = 0; r < 4; ++r) {
      int il = ig + r * 8;
      const float* p = C + (size_t)(i0 + il) * (O_DIM * 9) + (size_t)(o0 + ol) * 9;
      float c1 = p[1];
      float c2 = p[2], c3 = p[3], c4 = p[4], c5 = p[5], c6 = p[6], c7 = p[7], c8 = p[8];
      bsum += c1;
      unsigned short* q = &tile[ol * 192 + il * 6];
      q[0] = f2bf(c2 + c3);
      q[1] = f2bf(c4);
      q[2] = f2bf(c5);
      q[3] = f2bf(c6);
      q[4] = f2bf(c7);
      q[5] = f2bf(c8);
    }
    bred[t] = bsum;
    __syncthreads();
    if (t < 32) {
      float s = 0.f;
#pragma unroll
      for (int g = 0; g < 8; ++g) s += bred[g * 32 + t];
      partB[(size_t)(b & 31) * O_DIM + o0 + t] = s;
    }
    const u32x4* lsrc = (const u32x4*)tile;
#pragma unroll
    for (int r = 0; r < 3; ++r) {
      int c = t + r * 256;
      int row = c / 24, off = c % 24;
      u32x4* gdst = (u32x4*)(Bt + (size_t)(o0 + row) * K_DIM + (size_t)i0 * 6 + off * 8);
      *gdst = lsrc[c];
    }
  }
}

// ---------- Kernel 2b: final bias reduce (non-split fallback only) -----------
__global__ __launch_bounds__(256) void k_bias2(const float* __restrict__ partB,
                                               float* __restrict__ bias) {
  int o = blockIdx.x * 256 + threadIdx.x;     // 4 blocks
  float s = 0.f;
#pragma unroll
  for (int ib = 0; ib < 32; ++ib) s += partB[(size_t)ib * O_DIM + o];
  bias[o] = s;
}

// ---------------- Kernel 3: 256x256 bf16 GEMM, r7 read-ahead pipeline --------
// 512 thr = 8 waves (2M x 4N); per-wave C = 128x64. BK=64, LDS dbuf 128KB.
// Per tile: stage(nb) + readK(f1) issue, then 64 MFMA (f0 pre-read) covering
// all LDS reads + drains. One barrier/tile. SPLIT epilogue writes f16 partials
// in PERMUTED layout p = ((row>>2)*1024 + col)*4 + (row&3).
#define SBAR __builtin_amdgcn_sched_barrier(0)

template<bool SPLIT>
__global__ __launch_bounds__(512, 2) void k_gemm8(const unsigned short* __restrict__ A,
                                                  const unsigned short* __restrict__ B,
                                                  const float* __restrict__ bias,
                                                  _Float16* __restrict__ part,
                                                  float* __restrict__ out) {
  constexpr int CK = SPLIT ? (K_DIM / SPLITS) : K_DIM;   // 1536 / 6144
  constexpr int NT = CK / 64;                            // 24 / 96
  constexpr int PPX = SPLIT ? 8 : 2;                     // (ym,zk) panels per XCD
  __shared__ char lds[131072];   // [2 buf][A 32KB | B 32KB]
  const int tid = threadIdx.x;
  const int lane = tid & 63, wid = tid >> 6;
  const int wm = wid >> 2, wn = wid & 3;
  const int l15 = lane & 15, lk = lane >> 4, l7 = lane & 7;
  // XCD-grouped bijective remap: 4 n-blocks of one (ym,zk) panel -> same XCD
  const int flat = blockIdx.x + (blockIdx.y << 2) + (blockIdx.z << 6);
  const int xcd = flat & 7, slot = flat >> 3;
  const int panel = xcd * PPX + (slot >> 2);
  const int xn = slot & 3;
  const int ym = panel & 15, zk = panel >> 4;
  const int m0 = ym * 256, n0 = xn * 256;
  const size_t kb = (size_t)zk * CK;
  // staging: thread tid covers LDS rows tid>>3 (+64), chunk slot tid&7;
  // pre-swizzled global chunk = slot ^ (row&7)
  const int srow = tid >> 3;
  const int cg8 = (((tid & 7) ^ ((tid >> 3) & 7)) * 8);  // ushort offset
  // ds_read swizzled chunk offsets (row&7 == lane&7 for all frags)
  const int cx0 = (lk ^ l7) * 16;
  const int cx1 = ((4 + lk) ^ l7) * 16;
  const int arow = wm * 128 + l15;
  const int brow = wn * 64 + l15;

  auto gload = [&](const unsigned short* s, int ldsoff) {
    __builtin_amdgcn_global_load_lds((const __attribute__((address_space(1))) void*)s,
        (__attribute__((address_space(3))) void*)(lds + ldsoff), 16, 0, 0);
  };
  auto stageA = [&](int buf, int h, int kt2) {
    const unsigned short* s = A + (size_t)(m0 + h * 128 + srow) * K_DIM + kb + (size_t)kt2 * 64 + cg8;
    int d = buf * 65536 + h * 16384 + tid * 16;
    gload(s, d);
    gload(s + (size_t)64 * K_DIM, d + 8192);
  };
  auto stageB = [&](int buf, int h, int kt2) {
    const unsigned short* s = B + (size_t)(n0 + h * 128 + srow) * K_DIM + kb + (size_t)kt2 * 64 + cg8;
    int d = buf * 65536 + 32768 + h * 16384 + tid * 16;
    gload(s, d);
    gload(s + (size_t)64 * K_DIM, d + 8192);
  };

  // fragments: one K-half (12 x b128) per set
  short8 a0[8], b0v[4], a1[8], b1v[4];
  f32x4 acc[8][4];
#pragma unroll
  for (int i = 0; i < 8; ++i)
#pragma unroll
    for (int n = 0; n < 4; ++n)
#pragma unroll
      for (int j = 0; j < 4; ++j) acc[i][n][j] = 0.f;

  auto readK = [&](int buf, int cx, short8 (&av)[8], short8 (&bv)[4]) {
#pragma unroll
    for (int mi = 0; mi < 8; ++mi)
      av[mi] = *(const short8*)(lds + buf * 65536 + (arow + mi * 16) * 128 + cx);
#pragma unroll
    for (int ni = 0; ni < 4; ++ni)
      bv[ni] = *(const short8*)(lds + buf * 65536 + 32768 + (brow + ni * 16) * 128 + cx);
  };
  auto quadK = [&](short8 (&av)[8], short8 (&bv)[4]) {
#pragma unroll
    for (int mi = 0; mi < 8; ++mi)
#pragma unroll
      for (int ni = 0; ni < 4; ++ni)
        acc[mi][ni] = __builtin_amdgcn_mfma_f32_16x16x32_bf16(av[mi], bv[ni], acc[mi][ni], 0, 0, 0);
  };

  // prologue: stage tile0 into buf0, drain, barrier, read kc0 frags
  stageA(0, 0, 0); stageA(0, 1, 0); stageB(0, 0, 0); stageB(0, 1, 0);
  asm volatile("s_waitcnt vmcnt(0)" ::: "memory"); SBAR;
  __builtin_amdgcn_s_barrier(); SBAR;
  readK(0, cx0, a0, b0v);

#pragma unroll 1
  for (int kt = 0; kt < NT; ++kt) {
    const int buf = kt & 1, nb = buf ^ 1;
    if (kt + 1 < NT) {
      stageA(nb, 0, kt + 1); stageA(nb, 1, kt + 1);
      stageB(nb, 0, kt + 1); stageB(nb, 1, kt + 1);
    }
    readK(buf, cx1, a1, b1v);
    __builtin_amdgcn_s_setprio(1);
    quadK(a0, b0v);          // f0 pre-read: no wait at entry
    quadK(a1, b1v);          // counted lgkmcnt covers f1 reads
    __builtin_amdgcn_s_setprio(0); SBAR;
    asm volatile("s_waitcnt lgkmcnt(0)" ::: "memory"); SBAR;   // WAR: reads done
    if (kt + 1 < NT) {
      asm volatile("s_waitcnt vmcnt(0)" ::: "memory"); SBAR;   // RAW: staging done
      __builtin_amdgcn_s_barrier(); SBAR;
      readK(nb, cx0, a0, b0v);   // next tile f0: overlaps next issue + quad(f0)
    }
  }

  if (SPLIT) {
    // permuted partial layout: p = (g*1024 + col)*4 + rj, g = row>>2, rj = row&3
    _Float16* base = part + (size_t)zk * ((size_t)M_DIM * O_DIM);
    const int gb0 = (m0 >> 2) + wm * 32 + lk;
#pragma unroll
    for (int mi = 0; mi < 8; ++mi) {
      int g = gb0 + mi * 4;
#pragma unroll
      for (int ni = 0; ni < 4; ++ni) {
        int col = n0 + wn * 64 + ni * 16 + l15;
        h16x4 v;
#pragma unroll
        for (int j = 0; j < 4; ++j) v[j] = (_Float16)acc[mi][ni][j];
        *(h16x4*)(base + ((size_t)g * O_DIM + col) * 4) = v;   // 8B, lanes contiguous
      }
    }
  } else {
#pragma unroll
    for (int mi = 0; mi < 8; ++mi) {
      int r0 = m0 + wm * 128 + mi * 16 + (lk << 2);
#pragma unroll
      for (int ni = 0; ni < 4; ++ni) {
        int col = n0 + wn * 64 + ni * 16 + l15;
        float bv = bias[col];
#pragma unroll
        for (int j = 0; j < 4; ++j)
          out[(size_t)(r0 + j) * O_DIM + col] = acc[mi][ni][j] + bv;
      }
    }
  }
}

// ------ Kernel 4: reduce permuted f16 partials + in-block bias, via LDS ------
// Block b covers g = b>>1 (4 output rows), cols [(b&1)*512, +512).
// Bias computed per-thread from L2-resident partB (32 x float2, fixed order).
__global__ __launch_bounds__(256) void k_reduce(const _Float16* __restrict__ part,
                                                const float* __restrict__ partB,
                                                float* __restrict__ out) {
  __shared__ float lt[4][512];                 // [rj][local col]
  const int b = blockIdx.x, tt = threadIdx.x;  // 8192 blocks
  const size_t P = (size_t)M_DIM * O_DIM;
  size_t idx = (size_t)b * 2048 + (size_t)tt * 8;
  h16x8 s0 = *(const h16x8*)(part + idx);
  h16x8 s1 = *(const h16x8*)(part + P + idx);
  h16x8 s2 = *(const h16x8*)(part + 2 * P + idx);
  h16x8 s3 = *(const h16x8*)(part + 3 * P + idx);
  const int g = b >> 1;
  const int cbase = (b & 1) << 9;
  const int c0 = tt * 2;                       // local col of first group
  // bias for cols cbase+c0, cbase+c0+1: sum 32 partB rows (L2-hot, 8B loads)
  float bv0 = 0.f, bv1 = 0.f;
#pragma unroll 8
  for (int ib = 0; ib < 32; ++ib) {
    f32x2 p2 = *(const f32x2*)(partB + (size_t)ib * O_DIM + cbase + c0);
    bv0 += p2[0];
    bv1 += p2[1];
  }
#pragma unroll
  for (int k = 0; k < 8; ++k) {
    float r = (((float)s0[k] + (float)s1[k]) + ((float)s2[k] + (float)s3[k]))
              + ((k < 4) ? bv0 : bv1);
    lt[k & 3][c0 + (k >> 2)] = r;
  }
  __syncthreads();
  const int rj = tt >> 6, lc = (tt & 63) * 8;
  f32x4 v0 = *(const f32x4*)&lt[rj][lc];
  f32x4 v1 = *(const f32x4*)&lt[rj][lc + 4];
  float* o = out + (size_t)(4 * g + rj) * O_DIM + cbase + lc;
  *(f32x4*)o = v0;
  *(f32x4*)(o + 4) = v1;
}

extern "C" void kernel_launch(void* const* d_in, const int* in_sizes, int n_in,
                              void* d_out, int out_size, void* d_ws, size_t ws_size,
                              hipStream_t stream) {
  const float* x      = (const float*)d_in[0];
  const float* coeffs = (const float*)d_in[1];
  float* out = (float*)d_out;
  char* ws = (char*)d_ws;
  const size_t offA     = 0;
  const size_t offB     = 50331648;                // A: 4096*6144*2
  const size_t offBias  = offB + 12582912;         // Bt: 1024*6144*2
  const size_t offPartB = offBias + 4096;          // bias: 1024*4 (fallback only)
  const size_t offPart  = offPartB + 131072;       // partB: 32*1024*4
  const size_t needSplit = offPart + (size_t)SPLITS * M_DIM * O_DIM * 2;  // f16 partials

  unsigned short* A  = (unsigned short*)(ws + offA);
  unsigned short* Bt = (unsigned short*)(ws + offB);
  float* bias        = (float*)(ws + offBias);
  float* partB       = (float*)(ws + offPartB);
  _Float16* part     = (_Float16*)(ws + offPart);

  k_prep<<<3072, 256, 0, stream>>>(x, coeffs, A, Bt, partB);

  if (ws_size >= needSplit) {
    // 3-dispatch path: bias folded into k_reduce (partB is L2-resident there)
    k_gemm8<true><<<dim3(4, 16, SPLITS), 512, 0, stream>>>(A, Bt, bias, part, out);
    k_reduce<<<(M_DIM * O_DIM) / (256 * 8), 256, 0, stream>>>(part, partB, out);
  } else {
    k_bias2<<<4, 256, 0, stream>>>(partB, bias);
    k_gemm8<false><<<dim3(4, 16, 1), 512, 0, stream>>>(A, Bt, bias, part, out);
  }
}

// Round 17
// 86.168 us; speedup vs baseline: 1.0376x; 1.0376x over previous
//
#include <hip/hip_runtime.h>
#include <stdint.h>

#define M_DIM 4096
#define I_DIM 1024
#define O_DIM 1024
#define KB 6
#define K_DIM (I_DIM * KB)   // 6144
#define SPLITS 4

typedef __attribute__((ext_vector_type(8))) short short8;
typedef __attribute__((ext_vector_type(4))) float f32x4;
typedef __attribute__((ext_vector_type(4))) unsigned int u32x4;
typedef __attribute__((ext_vector_type(4))) float hfloat4;
typedef __attribute__((ext_vector_type(8))) _Float16 h16x8;
typedef __attribute__((ext_vector_type(4))) _Float16 h16x4;

__device__ __forceinline__ unsigned short f2bf(float f) {
  union { float f; unsigned int u; } v; v.f = f;
  unsigned int u = v.u;
  unsigned int r = (u + 0x7FFFu + ((u >> 16) & 1u)) >> 16;
  return (unsigned short)r;
}

// ---- Kernel 1 (fat): blocks [0,2048): basis planes -> bf16 A[4096][6144]
//                      blocks [2048,3072): coeffs -> bf16 Bt[1024][6144] + bias partials
__global__ __launch_bounds__(256) void k_prep(const float* __restrict__ x,
                                              const float* __restrict__ C,
                                              unsigned short* __restrict__ A,
                                              unsigned short* __restrict__ Bt,
                                              float* __restrict__ partB) {
  const int bid = blockIdx.x;
  if (bid < 2048) {
    int t = bid * 256 + threadIdx.x;
    long e0 = (long)t * 8;
    const hfloat4* xp = (const hfloat4*)(x + e0);
    hfloat4 v0 = xp[0], v1 = xp[1];
    float xv[8];
    xv[0]=v0[0]; xv[1]=v0[1]; xv[2]=v0[2]; xv[3]=v0[3];
    xv[4]=v1[0]; xv[5]=v1[1]; xv[6]=v1[2]; xv[7]=v1[3];
    unsigned short outv[48];
#pragma unroll
    for (int e = 0; e < 8; ++e) {
      float s  = 1.0f / (1.0f + __expf(-xv[e]));
      float b2 = s, b3 = s, b4 = s * s;
      float b5 = fmaf(s, b4, b3 + b2 + 1.0f);
      float b6 = fmaf(s, b5, b4 + b3 + b2 + 1.0f);
      float b7 = fmaf(s, b6, b5 + b4 + b3 + b2);
      float b8 = fmaf(s, b7, b6 + b5 + b4 + b3);
      outv[e*6+0] = f2bf(s);
      outv[e*6+1] = f2bf(b4);
      outv[e*6+2] = f2bf(b5);
      outv[e*6+3] = f2bf(b6);
      outv[e*6+4] = f2bf(b7);
      outv[e*6+5] = f2bf(b8);
    }
    u32x4* dst = (u32x4*)(A + e0 * KB);
    const u32x4* srcv = (const u32x4*)outv;
#pragma unroll
    for (int q = 0; q < 6; ++q) dst[q] = srcv[q];
  } else {
    __shared__ unsigned short tile[32 * 192];
    __shared__ float bred[256];
    int b = bid - 2048;
    int i0 = (b & 31) * 32, o0 = (b >> 5) * 32;
    int t = threadIdx.x;
    int ol = t & 31, ig = t >> 5;
    float bsum = 0.f;
#pragma unroll
    for (int r = 0; r < 4; ++r) {
      int il = ig + r * 8;
      const float* p = C + (size_t)(i0 + il) * (O_DIM * 9) + (size_t)(o0 + ol) * 9;
      float c1 = p[1];
      float c2 = p[2], c3 = p[3], c4 = p[4], c5 = p[5], c6 = p[6], c7 = p[7], c8 = p[8];
      bsum += c1;
      unsigned short* q = &tile[ol * 192 + il * 6];
      q[0] = f2bf(c2 + c3);
      q[1] = f2bf(c4);
      q[2] = f2bf(c5);
      q[3] = f2bf(c6);
      q[4] = f2bf(c7);
      q[5] = f2bf(c8);
    }
    bred[t] = bsum;
    __syncthreads();
    if (t < 32) {
      float s = 0.f;
#pragma unroll
      for (int g = 0; g < 8; ++g) s += bred[g * 32 + t];
      partB[(size_t)(b & 31) * O_DIM + o0 + t] = s;
    }
    const u32x4* lsrc = (const u32x4*)tile;
#pragma unroll
    for (int r = 0; r < 3; ++r) {
      int c = t + r * 256;
      int row = c / 24, off = c % 24;
      u32x4* gdst = (u32x4*)(Bt + (size_t)(o0 + row) * K_DIM + (size_t)i0 * 6 + off * 8);
      *gdst = lsrc[c];
    }
  }
}

// ---------------- Kernel 2b: final bias reduce (32 partials) -----------------
__global__ __launch_bounds__(256) void k_bias2(const float* __restrict__ partB,
                                               float* __restrict__ bias) {
  int o = blockIdx.x * 256 + threadIdx.x;     // 4 blocks
  float s = 0.f;
#pragma unroll
  for (int ib = 0; ib < 32; ++ib) s += partB[(size_t)ib * O_DIM + o];
  bias[o] = s;
}

// ---------------- Kernel 3: 256x256 bf16 GEMM, r7 read-ahead pipeline --------
// 512 thr = 8 waves (2M x 4N); per-wave C = 128x64. BK=64, LDS dbuf 128KB.
// Per tile: stage(nb) + readK(f1) issue, then 64 MFMA (f0 pre-read) covering
// all LDS reads + drains. One barrier/tile. SPLIT epilogue writes f16 partials
// in PERMUTED layout p = ((row>>2)*1024 + col)*4 + (row&3).
#define SBAR __builtin_amdgcn_sched_barrier(0)

template<bool SPLIT>
__global__ __launch_bounds__(512, 2) void k_gemm8(const unsigned short* __restrict__ A,
                                                  const unsigned short* __restrict__ B,
                                                  const float* __restrict__ bias,
                                                  _Float16* __restrict__ part,
                                                  float* __restrict__ out) {
  constexpr int CK = SPLIT ? (K_DIM / SPLITS) : K_DIM;   // 1536 / 6144
  constexpr int NT = CK / 64;                            // 24 / 96
  constexpr int PPX = SPLIT ? 8 : 2;                     // (ym,zk) panels per XCD
  __shared__ char lds[131072];   // [2 buf][A 32KB | B 32KB]
  const int tid = threadIdx.x;
  const int lane = tid & 63, wid = tid >> 6;
  const int wm = wid >> 2, wn = wid & 3;
  const int l15 = lane & 15, lk = lane >> 4, l7 = lane & 7;
  // XCD-grouped bijective remap: 4 n-blocks of one (ym,zk) panel -> same XCD
  const int flat = blockIdx.x + (blockIdx.y << 2) + (blockIdx.z << 6);
  const int xcd = flat & 7, slot = flat >> 3;
  const int panel = xcd * PPX + (slot >> 2);
  const int xn = slot & 3;
  const int ym = panel & 15, zk = panel >> 4;
  const int m0 = ym * 256, n0 = xn * 256;
  const size_t kb = (size_t)zk * CK;
  // staging: thread tid covers LDS rows tid>>3 (+64), chunk slot tid&7;
  // pre-swizzled global chunk = slot ^ (row&7)
  const int srow = tid >> 3;
  const int cg8 = (((tid & 7) ^ ((tid >> 3) & 7)) * 8);  // ushort offset
  // ds_read swizzled chunk offsets (row&7 == lane&7 for all frags)
  const int cx0 = (lk ^ l7) * 16;
  const int cx1 = ((4 + lk) ^ l7) * 16;
  const int arow = wm * 128 + l15;
  const int brow = wn * 64 + l15;

  auto gload = [&](const unsigned short* s, int ldsoff) {
    __builtin_amdgcn_global_load_lds((const __attribute__((address_space(1))) void*)s,
        (__attribute__((address_space(3))) void*)(lds + ldsoff), 16, 0, 0);
  };
  auto stageA = [&](int buf, int h, int kt2) {
    const unsigned short* s = A + (size_t)(m0 + h * 128 + srow) * K_DIM + kb + (size_t)kt2 * 64 + cg8;
    int d = buf * 65536 + h * 16384 + tid * 16;
    gload(s, d);
    gload(s + (size_t)64 * K_DIM, d + 8192);
  };
  auto stageB = [&](int buf, int h, int kt2) {
    const unsigned short* s = B + (size_t)(n0 + h * 128 + srow) * K_DIM + kb + (size_t)kt2 * 64 + cg8;
    int d = buf * 65536 + 32768 + h * 16384 + tid * 16;
    gload(s, d);
    gload(s + (size_t)64 * K_DIM, d + 8192);
  };

  // fragments: one K-half (12 x b128) per set
  short8 a0[8], b0v[4], a1[8], b1v[4];
  f32x4 acc[8][4];
#pragma unroll
  for (int i = 0; i < 8; ++i)
#pragma unroll
    for (int n = 0; n < 4; ++n)
#pragma unroll
      for (int j = 0; j < 4; ++j) acc[i][n][j] = 0.f;

  auto readK = [&](int buf, int cx, short8 (&av)[8], short8 (&bv)[4]) {
#pragma unroll
    for (int mi = 0; mi < 8; ++mi)
      av[mi] = *(const short8*)(lds + buf * 65536 + (arow + mi * 16) * 128 + cx);
#pragma unroll
    for (int ni = 0; ni < 4; ++ni)
      bv[ni] = *(const short8*)(lds + buf * 65536 + 32768 + (brow + ni * 16) * 128 + cx);
  };
  auto quadK = [&](short8 (&av)[8], short8 (&bv)[4]) {
#pragma unroll
    for (int mi = 0; mi < 8; ++mi)
#pragma unroll
      for (int ni = 0; ni < 4; ++ni)
        acc[mi][ni] = __builtin_amdgcn_mfma_f32_16x16x32_bf16(av[mi], bv[ni], acc[mi][ni], 0, 0, 0);
  };

  // prologue: stage tile0 into buf0, drain, barrier, read kc0 frags
  stageA(0, 0, 0); stageA(0, 1, 0); stageB(0, 0, 0); stageB(0, 1, 0);
  asm volatile("s_waitcnt vmcnt(0)" ::: "memory"); SBAR;
  __builtin_amdgcn_s_barrier(); SBAR;
  readK(0, cx0, a0, b0v);

#pragma unroll 1
  for (int kt = 0; kt < NT; ++kt) {
    const int buf = kt & 1, nb = buf ^ 1;
    if (kt + 1 < NT) {
      stageA(nb, 0, kt + 1); stageA(nb, 1, kt + 1);
      stageB(nb, 0, kt + 1); stageB(nb, 1, kt + 1);
    }
    readK(buf, cx1, a1, b1v);
    __builtin_amdgcn_s_setprio(1);
    quadK(a0, b0v);          // f0 pre-read: no wait at entry
    quadK(a1, b1v);          // counted lgkmcnt covers f1 reads
    __builtin_amdgcn_s_setprio(0); SBAR;
    asm volatile("s_waitcnt lgkmcnt(0)" ::: "memory"); SBAR;   // WAR: reads done
    if (kt + 1 < NT) {
      asm volatile("s_waitcnt vmcnt(0)" ::: "memory"); SBAR;   // RAW: staging done
      __builtin_amdgcn_s_barrier(); SBAR;
      readK(nb, cx0, a0, b0v);   // next tile f0: overlaps next issue + quad(f0)
    }
  }

  if (SPLIT) {
    // permuted partial layout: p = (g*1024 + col)*4 + rj, g = row>>2, rj = row&3
    _Float16* base = part + (size_t)zk * ((size_t)M_DIM * O_DIM);
    const int gb0 = (m0 >> 2) + wm * 32 + lk;
#pragma unroll
    for (int mi = 0; mi < 8; ++mi) {
      int g = gb0 + mi * 4;
#pragma unroll
      for (int ni = 0; ni < 4; ++ni) {
        int col = n0 + wn * 64 + ni * 16 + l15;
        h16x4 v;
#pragma unroll
        for (int j = 0; j < 4; ++j) v[j] = (_Float16)acc[mi][ni][j];
        *(h16x4*)(base + ((size_t)g * O_DIM + col) * 4) = v;   // 8B, lanes contiguous
      }
    }
  } else {
#pragma unroll
    for (int mi = 0; mi < 8; ++mi) {
      int r0 = m0 + wm * 128 + mi * 16 + (lk << 2);
#pragma unroll
      for (int ni = 0; ni < 4; ++ni) {
        int col = n0 + wn * 64 + ni * 16 + l15;
        float bv = bias[col];
#pragma unroll
        for (int j = 0; j < 4; ++j)
          out[(size_t)(r0 + j) * O_DIM + col] = acc[mi][ni][j] + bv;
      }
    }
  }
}

// ------ Kernel 4: reduce permuted f16 partials + bias, un-permute via LDS ----
__global__ __launch_bounds__(256) void k_reduce(const _Float16* __restrict__ part,
                                                const float* __restrict__ bias,
                                                float* __restrict__ out) {
  __shared__ float lt[4][512];                 // [rj][local col]
  const int b = blockIdx.x, tt = threadIdx.x;  // 2048 blocks
  const size_t P = (size_t)M_DIM * O_DIM;
  size_t idx = (size_t)b * 2048 + (size_t)tt * 8;
  h16x8 s0 = *(const h16x8*)(part + idx);
  h16x8 s1 = *(const h16x8*)(part + P + idx);
  h16x8 s2 = *(const h16x8*)(part + 2 * P + idx);
  h16x8 s3 = *(const h16x8*)(part + 3 * P + idx);
  const int g = b >> 1;
  const int cbase = (b & 1) << 9;
  const int c0 = tt * 2;
  float bv0 = bias[cbase + c0], bv1 = bias[cbase + c0 + 1];
#pragma unroll
  for (int k = 0; k < 8; ++k) {
    float r = (((float)s0[k] + (float)s1[k]) + ((float)s2[k] + (float)s3[k]))
              + ((k < 4) ? bv0 : bv1);
    lt[k & 3][c0 + (k >> 2)] = r;
  }
  __syncthreads();
  const int rj = tt >> 6, lc = (tt & 63) * 8;
  f32x4 v0 = *(const f32x4*)&lt[rj][lc];
  f32x4 v1 = *(const f32x4*)&lt[rj][lc + 4];
  float* o = out + (size_t)(4 * g + rj) * O_DIM + cbase + lc;
  *(f32x4*)o = v0;
  *(f32x4*)(o + 4) = v1;
}

extern "C" void kernel_launch(void* const* d_in, const int* in_sizes, int n_in,
                              void* d_out, int out_size, void* d_ws, size_t ws_size,
                              hipStream_t stream) {
  const float* x      = (const float*)d_in[0];
  const float* coeffs = (const float*)d_in[1];
  float* out = (float*)d_out;
  char* ws = (char*)d_ws;
  const size_t offA     = 0;
  const size_t offB     = 50331648;                // A: 4096*6144*2
  const size_t offBias  = offB + 12582912;         // Bt: 1024*6144*2
  const size_t offPartB = offBias + 4096;          // bias: 1024*4
  const size_t offPart  = offPartB + 131072;       // partB: 32*1024*4
  const size_t needSplit = offPart + (size_t)SPLITS * M_DIM * O_DIM * 2;  // f16 partials

  unsigned short* A  = (unsigned short*)(ws + offA);
  unsigned short* Bt = (unsigned short*)(ws + offB);
  float* bias        = (float*)(ws + offBias);
  float* partB       = (float*)(ws + offPartB);
  _Float16* part     = (_Float16*)(ws + offPart);

  k_prep<<<3072, 256, 0, stream>>>(x, coeffs, A, Bt, partB);
  k_bias2<<<4, 256, 0, stream>>>(partB, bias);

  if (ws_size >= needSplit) {
    k_gemm8<true><<<dim3(4, 16, SPLITS), 512, 0, stream>>>(A, Bt, bias, part, out);
    k_reduce<<<(M_DIM * O_DIM) / (256 * 8), 256, 0, stream>>>(part, bias, out);
  } else {
    k_gemm8<false><<<dim3(4, 16, 1), 512, 0, stream>>>(A, Bt, bias, part, out);
  }
}